// Round 1
// baseline (1697.427 us; speedup 1.0000x reference)
//
#include <hip/hip_runtime.h>

#define T_SEQ 2048
#define C_DIM 1024
#define NH    16
#define NKV   4
#define HD    64
#define WIN   512
#define QBQ   4

typedef __bf16 bf16x8 __attribute__((ext_vector_type(8)));
typedef __bf16 bf16x4 __attribute__((ext_vector_type(4)));
typedef float f32x4 __attribute__((ext_vector_type(4)));

// ---------------- cast f32 -> bf16 ----------------
__global__ __launch_bounds__(256) void cast_bf16_kernel(const float* __restrict__ in,
                                                        __bf16* __restrict__ out, int n) {
  int i = (blockIdx.x * 256 + threadIdx.x) * 4;
  if (i < n) {
    float4 v = *(const float4*)(in + i);
    bf16x4 o;
    o[0] = (__bf16)v.x; o[1] = (__bf16)v.y; o[2] = (__bf16)v.z; o[3] = (__bf16)v.w;
    *(bf16x4*)(out + i) = o;
  }
}

// ---------------- C[M,N] f32 = A[M,K]bf16 * B[N,K]bf16 ^T  (NT GEMM, MFMA) ----------------
// 64x64 tile, BK=32, 256 threads (4 waves); wave w computes rows [w*16,w*16+16) x 64 cols.
__global__ __launch_bounds__(256) void gemm_nt_kernel(const __bf16* __restrict__ A,
                                                      const __bf16* __restrict__ B,
                                                      float* __restrict__ C,
                                                      int M, int N, int K) {
  __shared__ __align__(16) __bf16 As[64 * 32];
  __shared__ __align__(16) __bf16 Bs[64 * 32];
  const int tid = threadIdx.x;
  const int w = tid >> 6;
  const int l = tid & 63;
  const int m0 = blockIdx.y * 64;
  const int n0 = blockIdx.x * 64;
  // staging: wave w fills rows [w*16, w*16+16) of the 64x32 tile; lane l -> row w*16+l/4, col 8*(l%4)
  const int srow = l >> 2;
  const int scol = (l & 3) * 8;
  const __bf16* gA = A + (size_t)(m0 + w * 16 + srow) * K + scol;
  const __bf16* gB = B + (size_t)(n0 + w * 16 + srow) * K + scol;
  __bf16* lA = As + w * 512;  // wave-uniform LDS base; HW scatters lane*16B
  __bf16* lB = Bs + w * 512;
  const int quad = l >> 4;   // 0..3
  const int r16 = l & 15;    // 0..15
  f32x4 acc0 = {0.f, 0.f, 0.f, 0.f};
  f32x4 acc1 = acc0, acc2 = acc0, acc3 = acc0;
  for (int k0 = 0; k0 < K; k0 += 32) {
    __builtin_amdgcn_global_load_lds((const __attribute__((address_space(1))) void*)(gA + k0),
                                     (__attribute__((address_space(3))) void*)lA, 16, 0, 0);
    __builtin_amdgcn_global_load_lds((const __attribute__((address_space(1))) void*)(gB + k0),
                                     (__attribute__((address_space(3))) void*)lB, 16, 0, 0);
    __syncthreads();
    // A frag: A[m=r16][k=quad*8+j]; B frag: B[n=r16][k=quad*8+j]
    bf16x8 af = *(const bf16x8*)(As + (w * 16 + r16) * 32 + quad * 8);
    bf16x8 b0 = *(const bf16x8*)(Bs + (0 * 16 + r16) * 32 + quad * 8);
    bf16x8 b1 = *(const bf16x8*)(Bs + (1 * 16 + r16) * 32 + quad * 8);
    bf16x8 b2 = *(const bf16x8*)(Bs + (2 * 16 + r16) * 32 + quad * 8);
    bf16x8 b3 = *(const bf16x8*)(Bs + (3 * 16 + r16) * 32 + quad * 8);
    acc0 = __builtin_amdgcn_mfma_f32_16x16x32_bf16(af, b0, acc0, 0, 0, 0);
    acc1 = __builtin_amdgcn_mfma_f32_16x16x32_bf16(af, b1, acc1, 0, 0, 0);
    acc2 = __builtin_amdgcn_mfma_f32_16x16x32_bf16(af, b2, acc2, 0, 0, 0);
    acc3 = __builtin_amdgcn_mfma_f32_16x16x32_bf16(af, b3, acc3, 0, 0, 0);
    __syncthreads();
  }
  // C/D layout: col(n)=lane&15, row(m)=quad*4+reg
  const int mrow = m0 + w * 16 + quad * 4;
  const int ncol = n0 + r16;
#pragma unroll
  for (int r = 0; r < 4; ++r) {
    size_t rowoff = (size_t)(mrow + r) * N;
    C[rowoff + ncol]      = acc0[r];
    C[rowoff + ncol + 16] = acc1[r];
    C[rowoff + ncol + 32] = acc2[r];
    C[rowoff + ncol + 48] = acc3[r];
  }
}

// ---------------- QK L2-norm + RoPE; relayout to [head][t][d] ----------------
// grid (T, 5), block 256: head = blockIdx.y*4 + tid/64 in [0,20); head<16 -> Q, else K.
__global__ __launch_bounds__(256) void norm_rope_kernel(const float* __restrict__ Qf,
                                                        const float* __restrict__ KVf,
                                                        float* __restrict__ Qn,
                                                        float* __restrict__ Kn) {
  const int t = blockIdx.x;
  const int head = blockIdx.y * 4 + (threadIdx.x >> 6);
  const int j = threadIdx.x & 63;
  float v;
  if (head < NH) v = Qf[(size_t)t * C_DIM + head * HD + j];
  else           v = KVf[(size_t)t * 512 + (head - NH) * HD + j];
  // L2 norm over head dim (before RoPE)
  float ss = v * v;
#pragma unroll
  for (int off = 32; off; off >>= 1) ss += __shfl_xor(ss, off, 64);
  v *= 1.0f / (sqrtf(ss) + 1e-6f);
  // RoPE: rot = concat(-v[32:64], v[0:32]); angle = t * 10000^(-(j%32)/32)
  float p = __shfl_xor(v, 32, 64);
  float rot = (j < 32) ? -p : p;
  const int i = j & 31;
  const float theta = exp2f(-(float)i * (13.287712379549449f / 32.0f));
  float ang = (float)t * theta;
  float s, c;
  sincosf(ang, &s, &c);
  float o = v * c + rot * s;
  if (head < NH) Qn[((size_t)head * T_SEQ + t) * HD + j] = o;
  else           Kn[((size_t)(head - NH) * T_SEQ + t) * HD + j] = o;
}

// ---------------- sliding-window attention, fp32, 4 queries/block ----------------
// grid (T/QBQ, NH), block 256. Qn:[H][T][64], Kn:[KV][T][64], V read from KVf:[T][512] cols 256..511.
__global__ __launch_bounds__(256) void attn_kernel(const float* __restrict__ Qn,
                                                   const float* __restrict__ Kn,
                                                   const float* __restrict__ KVf,
                                                   __bf16* __restrict__ Yb) {
  __shared__ __align__(16) float qs[QBQ * 64];
  __shared__ __align__(16) float sc[QBQ * (WIN + QBQ)];  // 4 x 516
  __shared__ __align__(16) float part[4 * QBQ * 64];
  __shared__ float invden[QBQ];
  const int h = blockIdx.y;
  const int kvh = h >> 2;  // repeat_interleave: head h uses kv head h/4
  const int t0 = blockIdx.x * QBQ;
  const int tid = threadIdx.x;
  const float scale = 0.125f;  // 1/sqrt(64)
  // stage 4 q vectors
  {
    int q = tid >> 6, j = tid & 63;
    qs[tid] = Qn[((size_t)h * T_SEQ + t0 + q) * HD + j];
  }
  __syncthreads();
  const int tmax = t0 + QBQ - 1;
  const int j0 = max(0, t0 - (WIN - 1));
  const int L = tmax - j0 + 1;  // <= 515
  // phase 1: scores for all 4 queries
  for (int kk = tid; kk < L; kk += 256) {
    const float* krow = Kn + ((size_t)kvh * T_SEQ + j0 + kk) * HD;
    float a0 = 0, a1 = 0, a2 = 0, a3 = 0;
#pragma unroll
    for (int jj = 0; jj < 64; jj += 4) {
      float4 k4 = *(const float4*)(krow + jj);
      float4 q0 = *(const float4*)(qs + jj);
      float4 q1 = *(const float4*)(qs + 64 + jj);
      float4 q2 = *(const float4*)(qs + 128 + jj);
      float4 q3 = *(const float4*)(qs + 192 + jj);
      a0 += k4.x * q0.x + k4.y * q0.y + k4.z * q0.z + k4.w * q0.w;
      a1 += k4.x * q1.x + k4.y * q1.y + k4.z * q1.z + k4.w * q1.w;
      a2 += k4.x * q2.x + k4.y * q2.y + k4.z * q2.z + k4.w * q2.w;
      a3 += k4.x * q3.x + k4.y * q3.y + k4.z * q3.z + k4.w * q3.w;
    }
    sc[0 * 516 + kk] = a0 * scale;
    sc[1 * 516 + kk] = a1 * scale;
    sc[2 * 516 + kk] = a2 * scale;
    sc[3 * 516 + kk] = a3 * scale;
  }
  __syncthreads();
  // phase 2: softmax (wave wq handles query wq)
  {
    const int wq = tid >> 6, lane = tid & 63;
    const int tq = t0 + wq;
    const int lo = max(0, tq - (WIN - 1)) - j0;
    const int hi = tq - j0;
    float m = -1e30f;
    for (int kk = lane; kk < L; kk += 64) {
      float s = (kk >= lo && kk <= hi) ? sc[wq * 516 + kk] : -1e30f;
      m = fmaxf(m, s);
    }
#pragma unroll
    for (int off = 32; off; off >>= 1) m = fmaxf(m, __shfl_xor(m, off, 64));
    float sum = 0.f;
    for (int kk = lane; kk < L; kk += 64) {
      bool valid = (kk >= lo && kk <= hi);
      float pv = valid ? __expf(sc[wq * 516 + kk] - m) : 0.f;
      sc[wq * 516 + kk] = pv;
      sum += pv;
    }
#pragma unroll
    for (int off = 32; off; off >>= 1) sum += __shfl_xor(sum, off, 64);
    if (lane == 0) invden[wq] = 1.0f / sum;
  }
  __syncthreads();
  // phase 3: PV. thread (j = tid&63, c = tid>>6); keys strided by 4 chunks.
  {
    const int j = tid & 63, c = tid >> 6;
    float a0 = 0, a1 = 0, a2 = 0, a3 = 0;
    for (int kk = c; kk < L; kk += 4) {
      float v = KVf[(size_t)(j0 + kk) * 512 + 256 + kvh * HD + j];
      a0 += sc[0 * 516 + kk] * v;
      a1 += sc[1 * 516 + kk] * v;
      a2 += sc[2 * 516 + kk] * v;
      a3 += sc[3 * 516 + kk] * v;
    }
    part[(c * QBQ + 0) * 64 + j] = a0;
    part[(c * QBQ + 1) * 64 + j] = a1;
    part[(c * QBQ + 2) * 64 + j] = a2;
    part[(c * QBQ + 3) * 64 + j] = a3;
  }
  __syncthreads();
  {
    const int q = tid >> 6, j = tid & 63;
    float o = part[(0 * QBQ + q) * 64 + j] + part[(1 * QBQ + q) * 64 + j] +
              part[(2 * QBQ + q) * 64 + j] + part[(3 * QBQ + q) * 64 + j];
    o *= invden[q];
    Yb[(size_t)(t0 + q) * C_DIM + h * HD + j] = (__bf16)o;
  }
}

extern "C" void kernel_launch(void* const* d_in, const int* in_sizes, int n_in,
                              void* d_out, int out_size, void* d_ws, size_t ws_size,
                              hipStream_t stream) {
  const float* x     = (const float*)d_in[0];
  const float* Wq    = (const float*)d_in[1];
  const float* Wkv   = (const float*)d_in[2];
  const float* Wproj = (const float*)d_in[3];
  float* out = (float*)d_out;

  // workspace layout
  __bf16* xb   = (__bf16*)d_ws;                    // 2048*1024
  __bf16* Wqb  = xb + T_SEQ * C_DIM;               // 1024*1024
  __bf16* Wkvb = Wqb + C_DIM * C_DIM;              // 512*1024
  __bf16* Wpb  = Wkvb + 512 * C_DIM;               // 1024*1024
  float*  Qf   = (float*)(Wpb + C_DIM * C_DIM);    // 2048*1024
  float*  KVf  = Qf + T_SEQ * C_DIM;               // 2048*512
  float*  Qn   = KVf + T_SEQ * 512;                // 2048*1024  [H][T][64]
  float*  Kn   = Qn + T_SEQ * C_DIM;               // 4*2048*64  [KV][T][64]
  __bf16* Yb   = (__bf16*)(Kn + NKV * T_SEQ * HD); // 2048*1024

  // casts
  cast_bf16_kernel<<<T_SEQ * C_DIM / 1024, 256, 0, stream>>>(x, xb, T_SEQ * C_DIM);
  cast_bf16_kernel<<<C_DIM * C_DIM / 1024, 256, 0, stream>>>(Wq, Wqb, C_DIM * C_DIM);
  cast_bf16_kernel<<<512 * C_DIM / 1024, 256, 0, stream>>>(Wkv, Wkvb, 512 * C_DIM);
  cast_bf16_kernel<<<C_DIM * C_DIM / 1024, 256, 0, stream>>>(Wproj, Wpb, C_DIM * C_DIM);

  // Q = x @ Wq^T  [2048,1024];  KV = x @ Wkv^T  [2048,512]
  gemm_nt_kernel<<<dim3(C_DIM / 64, T_SEQ / 64), 256, 0, stream>>>(xb, Wqb, Qf, T_SEQ, C_DIM, C_DIM);
  gemm_nt_kernel<<<dim3(512 / 64, T_SEQ / 64), 256, 0, stream>>>(xb, Wkvb, KVf, T_SEQ, 512, C_DIM);

  // L2 norm + RoPE, relayout
  norm_rope_kernel<<<dim3(T_SEQ, 5), 256, 0, stream>>>(Qf, KVf, Qn, Kn);

  // sliding-window attention -> Yb (bf16)
  attn_kernel<<<dim3(T_SEQ / QBQ, NH), 256, 0, stream>>>(Qn, Kn, KVf, Yb);

  // out = Y @ Wproj^T
  gemm_nt_kernel<<<dim3(C_DIM / 64, T_SEQ / 64), 256, 0, stream>>>(Yb, Wpb, out, T_SEQ, C_DIM, C_DIM);
}

// Round 2
// 327.078 us; speedup vs baseline: 5.1897x; 5.1897x over previous
//
#include <hip/hip_runtime.h>

#define T_SEQ 2048
#define C_DIM 1024
#define NH    16
#define NKV   4
#define HD    64
#define WIN   512
#define QBQ   4

typedef __bf16 bf16x8 __attribute__((ext_vector_type(8)));
typedef __bf16 bf16x4 __attribute__((ext_vector_type(4)));
typedef float f32x4 __attribute__((ext_vector_type(4)));

// ---------------- cast f32 -> bf16 ----------------
__global__ __launch_bounds__(256) void cast_bf16_kernel(const float* __restrict__ in,
                                                        __bf16* __restrict__ out, int n) {
  int i = (blockIdx.x * 256 + threadIdx.x) * 4;
  if (i < n) {
    float4 v = *(const float4*)(in + i);
    bf16x4 o;
    o[0] = (__bf16)v.x; o[1] = (__bf16)v.y; o[2] = (__bf16)v.z; o[3] = (__bf16)v.w;
    *(bf16x4*)(out + i) = o;
  }
}

// ---------------- C[M,N] f32 = A[M,K]bf16 * B[N,K]bf16 ^T  (NT GEMM, MFMA) ----------------
// 64x64 tile, BK=32, 256 threads (4 waves); wave w computes rows [w*16,w*16+16) x 64 cols.
__global__ __launch_bounds__(256) void gemm_nt_kernel(const __bf16* __restrict__ A,
                                                      const __bf16* __restrict__ B,
                                                      float* __restrict__ C,
                                                      int M, int N, int K) {
  __shared__ __align__(16) __bf16 As[64 * 32];
  __shared__ __align__(16) __bf16 Bs[64 * 32];
  const int tid = threadIdx.x;
  const int w = tid >> 6;
  const int l = tid & 63;
  const int m0 = blockIdx.y * 64;
  const int n0 = blockIdx.x * 64;
  // staging: wave w fills rows [w*16, w*16+16) of the 64x32 tile; lane l -> row w*16+l/4, col 8*(l%4)
  const int srow = l >> 2;
  const int scol = (l & 3) * 8;
  const __bf16* gA = A + (size_t)(m0 + w * 16 + srow) * K + scol;
  const __bf16* gB = B + (size_t)(n0 + w * 16 + srow) * K + scol;
  __bf16* lA = As + w * 512;  // wave-uniform LDS base; HW scatters lane*16B
  __bf16* lB = Bs + w * 512;
  const int quad = l >> 4;   // 0..3
  const int r16 = l & 15;    // 0..15
  f32x4 acc0 = {0.f, 0.f, 0.f, 0.f};
  f32x4 acc1 = acc0, acc2 = acc0, acc3 = acc0;
  for (int k0 = 0; k0 < K; k0 += 32) {
    __builtin_amdgcn_global_load_lds((const __attribute__((address_space(1))) void*)(gA + k0),
                                     (__attribute__((address_space(3))) void*)lA, 16, 0, 0);
    __builtin_amdgcn_global_load_lds((const __attribute__((address_space(1))) void*)(gB + k0),
                                     (__attribute__((address_space(3))) void*)lB, 16, 0, 0);
    __syncthreads();
    // A frag: A[m=r16][k=quad*8+j]; B frag: B[n=r16][k=quad*8+j]
    bf16x8 af = *(const bf16x8*)(As + (w * 16 + r16) * 32 + quad * 8);
    bf16x8 b0 = *(const bf16x8*)(Bs + (0 * 16 + r16) * 32 + quad * 8);
    bf16x8 b1 = *(const bf16x8*)(Bs + (1 * 16 + r16) * 32 + quad * 8);
    bf16x8 b2 = *(const bf16x8*)(Bs + (2 * 16 + r16) * 32 + quad * 8);
    bf16x8 b3 = *(const bf16x8*)(Bs + (3 * 16 + r16) * 32 + quad * 8);
    acc0 = __builtin_amdgcn_mfma_f32_16x16x32_bf16(af, b0, acc0, 0, 0, 0);
    acc1 = __builtin_amdgcn_mfma_f32_16x16x32_bf16(af, b1, acc1, 0, 0, 0);
    acc2 = __builtin_amdgcn_mfma_f32_16x16x32_bf16(af, b2, acc2, 0, 0, 0);
    acc3 = __builtin_amdgcn_mfma_f32_16x16x32_bf16(af, b3, acc3, 0, 0, 0);
    __syncthreads();
  }
  // C/D layout: col(n)=lane&15, row(m)=quad*4+reg
  const int mrow = m0 + w * 16 + quad * 4;
  const int ncol = n0 + r16;
#pragma unroll
  for (int r = 0; r < 4; ++r) {
    size_t rowoff = (size_t)(mrow + r) * N;
    C[rowoff + ncol]      = acc0[r];
    C[rowoff + ncol + 16] = acc1[r];
    C[rowoff + ncol + 32] = acc2[r];
    C[rowoff + ncol + 48] = acc3[r];
  }
}

// ---------------- QK L2-norm + RoPE; relayout to [head][t][d] ----------------
// grid (T, 5), block 256: head = blockIdx.y*4 + tid/64 in [0,20); head<16 -> Q, else K.
__global__ __launch_bounds__(256) void norm_rope_kernel(const float* __restrict__ Qf,
                                                        const float* __restrict__ KVf,
                                                        float* __restrict__ Qn,
                                                        float* __restrict__ Kn) {
  const int t = blockIdx.x;
  const int head = blockIdx.y * 4 + (threadIdx.x >> 6);
  const int j = threadIdx.x & 63;
  float v;
  if (head < NH) v = Qf[(size_t)t * C_DIM + head * HD + j];
  else           v = KVf[(size_t)t * 512 + (head - NH) * HD + j];
  // L2 norm over head dim (before RoPE)
  float ss = v * v;
#pragma unroll
  for (int off = 32; off; off >>= 1) ss += __shfl_xor(ss, off, 64);
  v *= 1.0f / (sqrtf(ss) + 1e-6f);
  // RoPE: rot = concat(-v[32:64], v[0:32]); angle = t * 10000^(-(j%32)/32)
  float p = __shfl_xor(v, 32, 64);
  float rot = (j < 32) ? -p : p;
  const int i = j & 31;
  const float theta = exp2f(-(float)i * (13.287712379549449f / 32.0f));
  float ang = (float)t * theta;
  float s, c;
  sincosf(ang, &s, &c);
  float o = v * c + rot * s;
  if (head < NH) Qn[((size_t)head * T_SEQ + t) * HD + j] = o;
  else           Kn[((size_t)(head - NH) * T_SEQ + t) * HD + j] = o;
}

// ---------------- sliding-window attention, fp32, 4 queries/block ----------------
// grid (T/QBQ, NH), block 256. Qn:[H][T][64], Kn:[KV][T][64], V read from KVf:[T][512] cols 256..511.
// __launch_bounds__(256,4): cap VGPRs at ~128 (16 waves/CU min). R0 post-mortem: compiler
// hoisted 256 q-floats from LDS into VGPRs across the kk loop -> 256 VGPR + scratch spills
// (1.2 GB/dispatch HBM writes). The asm memory clobber per kk iteration forces q re-reads
// (same-address LDS reads broadcast, ~free); unroll 4 bounds in-iteration pressure.
__global__ __launch_bounds__(256, 4) void attn_kernel(const float* __restrict__ Qn,
                                                      const float* __restrict__ Kn,
                                                      const float* __restrict__ KVf,
                                                      __bf16* __restrict__ Yb) {
  __shared__ __align__(16) float qs[QBQ * 64];
  __shared__ __align__(16) float sc[QBQ * (WIN + QBQ)];  // 4 x 516
  __shared__ __align__(16) float part[4 * QBQ * 64];
  __shared__ float invden[QBQ];
  const int h = blockIdx.y;
  const int kvh = h >> 2;  // repeat_interleave: head h uses kv head h/4
  const int t0 = blockIdx.x * QBQ;
  const int tid = threadIdx.x;
  const float scale = 0.125f;  // 1/sqrt(64)
  // stage 4 q vectors
  {
    int q = tid >> 6, j = tid & 63;
    qs[tid] = Qn[((size_t)h * T_SEQ + t0 + q) * HD + j];
  }
  __syncthreads();
  const int tmax = t0 + QBQ - 1;
  const int j0 = max(0, t0 - (WIN - 1));
  const int L = tmax - j0 + 1;  // <= 515
  // phase 1: scores for all 4 queries
  for (int kk = tid; kk < L; kk += 256) {
    asm volatile("" ::: "memory");  // block LDS-value hoisting across kk iterations
    const float* krow = Kn + ((size_t)kvh * T_SEQ + j0 + kk) * HD;
    float a0 = 0, a1 = 0, a2 = 0, a3 = 0;
#pragma unroll 4
    for (int jj = 0; jj < 64; jj += 4) {
      float4 k4 = *(const float4*)(krow + jj);
      float4 q0 = *(const float4*)(qs + jj);
      float4 q1 = *(const float4*)(qs + 64 + jj);
      float4 q2 = *(const float4*)(qs + 128 + jj);
      float4 q3 = *(const float4*)(qs + 192 + jj);
      a0 += k4.x * q0.x + k4.y * q0.y + k4.z * q0.z + k4.w * q0.w;
      a1 += k4.x * q1.x + k4.y * q1.y + k4.z * q1.z + k4.w * q1.w;
      a2 += k4.x * q2.x + k4.y * q2.y + k4.z * q2.z + k4.w * q2.w;
      a3 += k4.x * q3.x + k4.y * q3.y + k4.z * q3.z + k4.w * q3.w;
    }
    sc[0 * 516 + kk] = a0 * scale;
    sc[1 * 516 + kk] = a1 * scale;
    sc[2 * 516 + kk] = a2 * scale;
    sc[3 * 516 + kk] = a3 * scale;
  }
  __syncthreads();
  // phase 2: softmax (wave wq handles query wq)
  {
    const int wq = tid >> 6, lane = tid & 63;
    const int tq = t0 + wq;
    const int lo = max(0, tq - (WIN - 1)) - j0;
    const int hi = tq - j0;
    float m = -1e30f;
    for (int kk = lane; kk < L; kk += 64) {
      float s = (kk >= lo && kk <= hi) ? sc[wq * 516 + kk] : -1e30f;
      m = fmaxf(m, s);
    }
#pragma unroll
    for (int off = 32; off; off >>= 1) m = fmaxf(m, __shfl_xor(m, off, 64));
    float sum = 0.f;
    for (int kk = lane; kk < L; kk += 64) {
      bool valid = (kk >= lo && kk <= hi);
      float pv = valid ? __expf(sc[wq * 516 + kk] - m) : 0.f;
      sc[wq * 516 + kk] = pv;
      sum += pv;
    }
#pragma unroll
    for (int off = 32; off; off >>= 1) sum += __shfl_xor(sum, off, 64);
    if (lane == 0) invden[wq] = 1.0f / sum;
  }
  __syncthreads();
  // phase 3: PV. thread (j = tid&63, c = tid>>6); keys strided by 4 chunks.
  {
    const int j = tid & 63, c = tid >> 6;
    float a0 = 0, a1 = 0, a2 = 0, a3 = 0;
    for (int kk = c; kk < L; kk += 4) {
      asm volatile("" ::: "memory");
      float v = KVf[(size_t)(j0 + kk) * 512 + 256 + kvh * HD + j];
      a0 += sc[0 * 516 + kk] * v;
      a1 += sc[1 * 516 + kk] * v;
      a2 += sc[2 * 516 + kk] * v;
      a3 += sc[3 * 516 + kk] * v;
    }
    part[(c * QBQ + 0) * 64 + j] = a0;
    part[(c * QBQ + 1) * 64 + j] = a1;
    part[(c * QBQ + 2) * 64 + j] = a2;
    part[(c * QBQ + 3) * 64 + j] = a3;
  }
  __syncthreads();
  {
    const int q = tid >> 6, j = tid & 63;
    float o = part[(0 * QBQ + q) * 64 + j] + part[(1 * QBQ + q) * 64 + j] +
              part[(2 * QBQ + q) * 64 + j] + part[(3 * QBQ + q) * 64 + j];
    o *= invden[q];
    Yb[(size_t)(t0 + q) * C_DIM + h * HD + j] = (__bf16)o;
  }
}

extern "C" void kernel_launch(void* const* d_in, const int* in_sizes, int n_in,
                              void* d_out, int out_size, void* d_ws, size_t ws_size,
                              hipStream_t stream) {
  const float* x     = (const float*)d_in[0];
  const float* Wq    = (const float*)d_in[1];
  const float* Wkv   = (const float*)d_in[2];
  const float* Wproj = (const float*)d_in[3];
  float* out = (float*)d_out;

  // workspace layout
  __bf16* xb   = (__bf16*)d_ws;                    // 2048*1024
  __bf16* Wqb  = xb + T_SEQ * C_DIM;               // 1024*1024
  __bf16* Wkvb = Wqb + C_DIM * C_DIM;              // 512*1024
  __bf16* Wpb  = Wkvb + 512 * C_DIM;               // 1024*1024
  float*  Qf   = (float*)(Wpb + C_DIM * C_DIM);    // 2048*1024
  float*  KVf  = Qf + T_SEQ * C_DIM;               // 2048*512
  float*  Qn   = KVf + T_SEQ * 512;                // 2048*1024  [H][T][64]
  float*  Kn   = Qn + T_SEQ * C_DIM;               // 4*2048*64  [KV][T][64]
  __bf16* Yb   = (__bf16*)(Kn + NKV * T_SEQ * HD); // 2048*1024

  // casts
  cast_bf16_kernel<<<T_SEQ * C_DIM / 1024, 256, 0, stream>>>(x, xb, T_SEQ * C_DIM);
  cast_bf16_kernel<<<C_DIM * C_DIM / 1024, 256, 0, stream>>>(Wq, Wqb, C_DIM * C_DIM);
  cast_bf16_kernel<<<512 * C_DIM / 1024, 256, 0, stream>>>(Wkv, Wkvb, 512 * C_DIM);
  cast_bf16_kernel<<<C_DIM * C_DIM / 1024, 256, 0, stream>>>(Wproj, Wpb, C_DIM * C_DIM);

  // Q = x @ Wq^T  [2048,1024];  KV = x @ Wkv^T  [2048,512]
  gemm_nt_kernel<<<dim3(C_DIM / 64, T_SEQ / 64), 256, 0, stream>>>(xb, Wqb, Qf, T_SEQ, C_DIM, C_DIM);
  gemm_nt_kernel<<<dim3(512 / 64, T_SEQ / 64), 256, 0, stream>>>(xb, Wkvb, KVf, T_SEQ, 512, C_DIM);

  // L2 norm + RoPE, relayout
  norm_rope_kernel<<<dim3(T_SEQ, 5), 256, 0, stream>>>(Qf, KVf, Qn, Kn);

  // sliding-window attention -> Yb (bf16)
  attn_kernel<<<dim3(T_SEQ / QBQ, NH), 256, 0, stream>>>(Qn, Kn, KVf, Yb);

  // out = Y @ Wproj^T
  gemm_nt_kernel<<<dim3(C_DIM / 64, T_SEQ / 64), 256, 0, stream>>>(Yb, Wpb, out, T_SEQ, C_DIM, C_DIM);
}

// Round 3
// 178.467 us; speedup vs baseline: 9.5112x; 1.8327x over previous
//
#include <hip/hip_runtime.h>

#define T_SEQ 2048
#define C_DIM 1024
#define NH    16
#define NKV   4
#define HD    64
#define WIN   512

typedef __bf16 bf16x8 __attribute__((ext_vector_type(8)));
typedef __bf16 bf16x4 __attribute__((ext_vector_type(4)));
typedef float f32x4 __attribute__((ext_vector_type(4)));

// ---------------- cast f32 -> bf16 ----------------
__global__ __launch_bounds__(256) void cast_bf16_kernel(const float* __restrict__ in,
                                                        __bf16* __restrict__ out, int n) {
  int i = (blockIdx.x * 256 + threadIdx.x) * 4;
  if (i < n) {
    float4 v = *(const float4*)(in + i);
    bf16x4 o;
    o[0] = (__bf16)v.x; o[1] = (__bf16)v.y; o[2] = (__bf16)v.z; o[3] = (__bf16)v.w;
    *(bf16x4*)(out + i) = o;
  }
}

// ---------------- C[M,N] f32 = A[M,K]bf16 * B[N,K]bf16 ^T  (NT GEMM, MFMA) ----------------
__global__ __launch_bounds__(256) void gemm_nt_kernel(const __bf16* __restrict__ A,
                                                      const __bf16* __restrict__ B,
                                                      float* __restrict__ C,
                                                      int M, int N, int K) {
  __shared__ __align__(16) __bf16 As[64 * 32];
  __shared__ __align__(16) __bf16 Bs[64 * 32];
  const int tid = threadIdx.x;
  const int w = tid >> 6;
  const int l = tid & 63;
  const int m0 = blockIdx.y * 64;
  const int n0 = blockIdx.x * 64;
  const int srow = l >> 2;
  const int scol = (l & 3) * 8;
  const __bf16* gA = A + (size_t)(m0 + w * 16 + srow) * K + scol;
  const __bf16* gB = B + (size_t)(n0 + w * 16 + srow) * K + scol;
  __bf16* lA = As + w * 512;
  __bf16* lB = Bs + w * 512;
  const int quad = l >> 4;
  const int r16 = l & 15;
  f32x4 acc0 = {0.f, 0.f, 0.f, 0.f};
  f32x4 acc1 = acc0, acc2 = acc0, acc3 = acc0;
  for (int k0 = 0; k0 < K; k0 += 32) {
    __builtin_amdgcn_global_load_lds((const __attribute__((address_space(1))) void*)(gA + k0),
                                     (__attribute__((address_space(3))) void*)lA, 16, 0, 0);
    __builtin_amdgcn_global_load_lds((const __attribute__((address_space(1))) void*)(gB + k0),
                                     (__attribute__((address_space(3))) void*)lB, 16, 0, 0);
    __syncthreads();
    bf16x8 af = *(const bf16x8*)(As + (w * 16 + r16) * 32 + quad * 8);
    bf16x8 b0 = *(const bf16x8*)(Bs + (0 * 16 + r16) * 32 + quad * 8);
    bf16x8 b1 = *(const bf16x8*)(Bs + (1 * 16 + r16) * 32 + quad * 8);
    bf16x8 b2 = *(const bf16x8*)(Bs + (2 * 16 + r16) * 32 + quad * 8);
    bf16x8 b3 = *(const bf16x8*)(Bs + (3 * 16 + r16) * 32 + quad * 8);
    acc0 = __builtin_amdgcn_mfma_f32_16x16x32_bf16(af, b0, acc0, 0, 0, 0);
    acc1 = __builtin_amdgcn_mfma_f32_16x16x32_bf16(af, b1, acc1, 0, 0, 0);
    acc2 = __builtin_amdgcn_mfma_f32_16x16x32_bf16(af, b2, acc2, 0, 0, 0);
    acc3 = __builtin_amdgcn_mfma_f32_16x16x32_bf16(af, b3, acc3, 0, 0, 0);
    __syncthreads();
  }
  const int mrow = m0 + w * 16 + quad * 4;
  const int ncol = n0 + r16;
#pragma unroll
  for (int r = 0; r < 4; ++r) {
    size_t rowoff = (size_t)(mrow + r) * N;
    C[rowoff + ncol]      = acc0[r];
    C[rowoff + ncol + 16] = acc1[r];
    C[rowoff + ncol + 32] = acc2[r];
    C[rowoff + ncol + 48] = acc3[r];
  }
}

// ---------------- QK L2-norm + RoPE -> bf16, relayout to [head][t][d] ----------------
// Qb gets the 1/sqrt(d)=0.125 softmax scale folded in (2^-3, exact in bf16).
__global__ __launch_bounds__(256) void norm_rope_kernel(const float* __restrict__ Qf,
                                                        const float* __restrict__ KVf,
                                                        __bf16* __restrict__ Qb,
                                                        __bf16* __restrict__ Kb) {
  const int t = blockIdx.x;
  const int head = blockIdx.y * 4 + (threadIdx.x >> 6);
  const int j = threadIdx.x & 63;
  float v;
  if (head < NH) v = Qf[(size_t)t * C_DIM + head * HD + j];
  else           v = KVf[(size_t)t * 512 + (head - NH) * HD + j];
  float ss = v * v;
#pragma unroll
  for (int off = 32; off; off >>= 1) ss += __shfl_xor(ss, off, 64);
  v *= 1.0f / (sqrtf(ss) + 1e-6f);
  float p = __shfl_xor(v, 32, 64);
  float rot = (j < 32) ? -p : p;
  const int i = j & 31;
  const float theta = exp2f(-(float)i * (13.287712379549449f / 32.0f));
  float ang = (float)t * theta;
  float s, c;
  sincosf(ang, &s, &c);
  float o = v * c + rot * s;
  if (head < NH) Qb[((size_t)head * T_SEQ + t) * HD + j] = (__bf16)(o * 0.125f);
  else           Kb[((size_t)(head - NH) * T_SEQ + t) * HD + j] = (__bf16)o;
}

// ---------------- V transpose: KVf[t][256 + kvh*64 + d] f32 -> Vt[kvh][d][t] bf16 ----------------
// grid (T/64, NKV), block 256
__global__ __launch_bounds__(256) void vtrans_kernel(const float* __restrict__ KVf,
                                                     __bf16* __restrict__ Vt) {
  __shared__ float ls[64][65];
  const int kvh = blockIdx.y;
  const int tb = blockIdx.x * 64;
  const int tid = threadIdx.x;
  {
    int r = tid >> 2, c0 = (tid & 3) * 16;
#pragma unroll
    for (int i = 0; i < 16; i += 4) {
      float4 v = *(const float4*)(KVf + (size_t)(tb + r) * 512 + 256 + kvh * 64 + c0 + i);
      ls[r][c0 + i] = v.x; ls[r][c0 + i + 1] = v.y;
      ls[r][c0 + i + 2] = v.z; ls[r][c0 + i + 3] = v.w;
    }
  }
  __syncthreads();
  {
    int d = tid >> 2, t0c = (tid & 3) * 16;
    bf16x8 o0, o1;
#pragma unroll
    for (int i = 0; i < 8; ++i) o0[i] = (__bf16)ls[t0c + i][d];
#pragma unroll
    for (int i = 0; i < 8; ++i) o1[i] = (__bf16)ls[t0c + 8 + i][d];
    __bf16* dst = Vt + ((size_t)kvh * HD + d) * T_SEQ + tb + t0c;
    *(bf16x8*)dst = o0;
    *(bf16x8*)(dst + 8) = o1;
  }
}

// ---------------- MFMA sliding-window attention ----------------
// grid (T/64, NH), block 256 (4 waves). Wave w owns queries [t0+w*16, t0+w*16+16).
// Per 64-key chunk: S = Q K^T (MFMA, scale pre-folded into Qb), mask+exp (|s|<=0.125 so
// no online max needed), P -> per-wave LDS (A-frag relayout), O += P V via MFMA on
// pre-transposed Vt. Row-sums in registers, shfl-reduced in epilogue.
__global__ __launch_bounds__(256) void attn_mfma_kernel(const __bf16* __restrict__ Qb,
                                                        const __bf16* __restrict__ Kb,
                                                        const __bf16* __restrict__ Vt,
                                                        __bf16* __restrict__ Yb) {
  __shared__ __align__(16) __bf16 Pl[4][16][72];  // per-wave P chunk; stride 72 keeps 16B align
  const int h = blockIdx.y, kvh = h >> 2;
  const int t0 = blockIdx.x * 64;
  const int tid = threadIdx.x;
  const int w = tid >> 6, l = tid & 63;
  const int quad = l >> 4, r16 = l & 15;
  // Q A-frags (A[m=r16][k=quad*8+j]) loaded once
  const __bf16* qptr = Qb + ((size_t)h * T_SEQ + t0 + w * 16 + r16) * HD + quad * 8;
  bf16x8 aq0 = *(const bf16x8*)(qptr);
  bf16x8 aq1 = *(const bf16x8*)(qptr + 32);
  const int j0 = max(0, t0 - WIN);
  const int nch = (t0 + 64 - j0) >> 6;
  const __bf16* kbase = Kb + (size_t)kvh * T_SEQ * HD;
  const __bf16* vbase = Vt + (size_t)kvh * HD * T_SEQ;
  const int tq_base = t0 + w * 16 + quad * 4;  // C-layout row base for this lane
  f32x4 oacc[4] = {};
  float lsum[4] = {0.f, 0.f, 0.f, 0.f};
  for (int c = 0; c < nch; ++c) {
    const int key0 = j0 + (c << 6);
    // scores: 4 key n-tiles x 2 k-steps
    f32x4 s[4] = {};
#pragma unroll
    for (int nt = 0; nt < 4; ++nt) {
      const __bf16* kr = kbase + (size_t)(key0 + nt * 16 + r16) * HD + quad * 8;
      bf16x8 bk0 = *(const bf16x8*)kr;
      bf16x8 bk1 = *(const bf16x8*)(kr + 32);
      s[nt] = __builtin_amdgcn_mfma_f32_16x16x32_bf16(aq0, bk0, s[nt], 0, 0, 0);
      s[nt] = __builtin_amdgcn_mfma_f32_16x16x32_bf16(aq1, bk1, s[nt], 0, 0, 0);
    }
    // mask + exp + P->LDS + running sum
#pragma unroll
    for (int nt = 0; nt < 4; ++nt) {
      const int key = key0 + nt * 16 + r16;
#pragma unroll
      for (int r = 0; r < 4; ++r) {
        const int tq = tq_base + r;
        bool valid = (key <= tq) && (key > tq - WIN);
        float p = valid ? __expf(s[nt][r]) : 0.0f;
        lsum[r] += p;
        Pl[w][quad * 4 + r][nt * 16 + r16] = (__bf16)p;
      }
    }
    // PV: A-frags from per-wave LDS (in-wave DS ordering, no barrier needed)
    bf16x8 ap0 = *(const bf16x8*)(&Pl[w][r16][quad * 8]);
    bf16x8 ap1 = *(const bf16x8*)(&Pl[w][r16][32 + quad * 8]);
#pragma unroll
    for (int nt = 0; nt < 4; ++nt) {
      const __bf16* vr = vbase + (size_t)(nt * 16 + r16) * T_SEQ + key0 + quad * 8;
      bf16x8 bv0 = *(const bf16x8*)vr;
      bf16x8 bv1 = *(const bf16x8*)(vr + 32);
      oacc[nt] = __builtin_amdgcn_mfma_f32_16x16x32_bf16(ap0, bv0, oacc[nt], 0, 0, 0);
      oacc[nt] = __builtin_amdgcn_mfma_f32_16x16x32_bf16(ap1, bv1, oacc[nt], 0, 0, 0);
    }
  }
  // reduce lsum across the 16 lanes of each quad group (key-cols), then normalize+store
#pragma unroll
  for (int r = 0; r < 4; ++r) {
#pragma unroll
    for (int m = 1; m < 16; m <<= 1) lsum[r] += __shfl_xor(lsum[r], m, 64);
    lsum[r] = 1.0f / lsum[r];
  }
#pragma unroll
  for (int r = 0; r < 4; ++r) {
    size_t row = (size_t)(tq_base + r);
#pragma unroll
    for (int nt = 0; nt < 4; ++nt) {
      Yb[row * C_DIM + h * HD + nt * 16 + r16] = (__bf16)(oacc[nt][r] * lsum[r]);
    }
  }
}

extern "C" void kernel_launch(void* const* d_in, const int* in_sizes, int n_in,
                              void* d_out, int out_size, void* d_ws, size_t ws_size,
                              hipStream_t stream) {
  const float* x     = (const float*)d_in[0];
  const float* Wq    = (const float*)d_in[1];
  const float* Wkv   = (const float*)d_in[2];
  const float* Wproj = (const float*)d_in[3];
  float* out = (float*)d_out;

  // workspace layout
  __bf16* xb   = (__bf16*)d_ws;                    // 2048*1024
  __bf16* Wqb  = xb + T_SEQ * C_DIM;               // 1024*1024
  __bf16* Wkvb = Wqb + C_DIM * C_DIM;              // 512*1024
  __bf16* Wpb  = Wkvb + 512 * C_DIM;               // 1024*1024
  float*  Qf   = (float*)(Wpb + C_DIM * C_DIM);    // 2048*1024 f32
  float*  KVf  = Qf + T_SEQ * C_DIM;               // 2048*512  f32
  __bf16* Qb   = (__bf16*)(KVf + T_SEQ * 512);     // [16][2048][64]
  __bf16* Kb   = Qb + (size_t)NH * T_SEQ * HD;     // [4][2048][64]
  __bf16* Vt   = Kb + (size_t)NKV * T_SEQ * HD;    // [4][64][2048]
  __bf16* Yb   = Vt + (size_t)NKV * HD * T_SEQ;    // 2048*1024

  // casts
  cast_bf16_kernel<<<T_SEQ * C_DIM / 1024, 256, 0, stream>>>(x, xb, T_SEQ * C_DIM);
  cast_bf16_kernel<<<C_DIM * C_DIM / 1024, 256, 0, stream>>>(Wq, Wqb, C_DIM * C_DIM);
  cast_bf16_kernel<<<512 * C_DIM / 1024, 256, 0, stream>>>(Wkv, Wkvb, 512 * C_DIM);
  cast_bf16_kernel<<<C_DIM * C_DIM / 1024, 256, 0, stream>>>(Wproj, Wpb, C_DIM * C_DIM);

  // Q = x @ Wq^T  [2048,1024];  KV = x @ Wkv^T  [2048,512]
  gemm_nt_kernel<<<dim3(C_DIM / 64, T_SEQ / 64), 256, 0, stream>>>(xb, Wqb, Qf, T_SEQ, C_DIM, C_DIM);
  gemm_nt_kernel<<<dim3(512 / 64, T_SEQ / 64), 256, 0, stream>>>(xb, Wkvb, KVf, T_SEQ, 512, C_DIM);

  // L2 norm + RoPE -> bf16 layouts; V transpose -> Vt bf16
  norm_rope_kernel<<<dim3(T_SEQ, 5), 256, 0, stream>>>(Qf, KVf, Qb, Kb);
  vtrans_kernel<<<dim3(T_SEQ / 64, NKV), 256, 0, stream>>>(KVf, Vt);

  // MFMA sliding-window attention -> Yb (bf16)
  attn_mfma_kernel<<<dim3(T_SEQ / 64, NH), 256, 0, stream>>>(Qb, Kb, Vt, Yb);

  // out = Y @ Wproj^T
  gemm_nt_kernel<<<dim3(C_DIM / 64, T_SEQ / 64), 256, 0, stream>>>(Yb, Wpb, out, T_SEQ, C_DIM, C_DIM);
}

// Round 4
// 160.330 us; speedup vs baseline: 10.5871x; 1.1131x over previous
//
#include <hip/hip_runtime.h>

#define T_SEQ 2048
#define C_DIM 1024
#define NH    16
#define NKV   4
#define HD    64
#define WIN   512

typedef __bf16 bf16x8 __attribute__((ext_vector_type(8)));
typedef __bf16 bf16x4 __attribute__((ext_vector_type(4)));
typedef float f32x4 __attribute__((ext_vector_type(4)));

// ---------------- fused cast f32 -> bf16 for all 4 inputs ----------------
// block ranges (1024 elements each): x[0,2048) Wq[2048,3072) Wkv[3072,3584) Wp[3584,4608)
// Wq and Wkv land contiguously in Wqkvb[1536][1024] (rows 0..1023 = Wq, 1024..1535 = Wkv).
__global__ __launch_bounds__(256) void cast_all_kernel(const float* __restrict__ x,
                                                       const float* __restrict__ Wq,
                                                       const float* __restrict__ Wkv,
                                                       const float* __restrict__ Wp,
                                                       __bf16* __restrict__ xb,
                                                       __bf16* __restrict__ Wqkvb,
                                                       __bf16* __restrict__ Wpb) {
  int b = blockIdx.x;
  const float* src;
  __bf16* dst;
  int off;
  if (b < 2048)      { src = x;   dst = xb;                  off = b; }
  else if (b < 3072) { src = Wq;  dst = Wqkvb;               off = b - 2048; }
  else if (b < 3584) { src = Wkv; dst = Wqkvb + (1 << 20);   off = b - 3072; }
  else               { src = Wp;  dst = Wpb;                 off = b - 3584; }
  int i = off * 1024 + threadIdx.x * 4;
  float4 v = *(const float4*)(src + i);
  bf16x4 o;
  o[0] = (__bf16)v.x; o[1] = (__bf16)v.y; o[2] = (__bf16)v.z; o[3] = (__bf16)v.w;
  *(bf16x4*)(dst + i) = o;
}

// ---------------- C[M,N] f32 = A[M,K]bf16 * B[N,K]bf16 ^T  (NT GEMM, MFMA) ----------------
// 128(M)x64(N) tile, BK=32, 256 threads / 4 waves. Wave w owns rows [w*32, w*32+32) x 64 cols
// (2x4 16x16 acc tiles). Per K-step: 3 global_load_lds(16B) + 6 ds_read_b128 + 8 MFMA per wave
// (vs 2:5:4 for the old 64x64 tile) -> 2x MFMA density per barrier. Grid stays >=256 blocks
// at these shapes (128x128 tile would drop proj to 128 blocks = half the CUs idle).
__global__ __launch_bounds__(256) void gemm_nt128_kernel(const __bf16* __restrict__ A,
                                                         const __bf16* __restrict__ B,
                                                         float* __restrict__ C,
                                                         int M, int N, int K) {
  __shared__ __align__(16) __bf16 As[128 * 32];
  __shared__ __align__(16) __bf16 Bs[64 * 32];
  const int tid = threadIdx.x;
  const int w = tid >> 6;
  const int l = tid & 63;
  const int m0 = blockIdx.y * 128;
  const int n0 = blockIdx.x * 64;
  const int srow = l >> 2;          // 0..15
  const int scol = (l & 3) * 8;     // 0,8,16,24
  // staging ptrs: As call0 rows 0..63, call1 rows 64..127; Bs rows 0..63
  const __bf16* gA0 = A + (size_t)(m0 + w * 16 + srow) * K + scol;
  const __bf16* gA1 = A + (size_t)(m0 + 64 + w * 16 + srow) * K + scol;
  const __bf16* gB  = B + (size_t)(n0 + w * 16 + srow) * K + scol;
  __bf16* lA0 = As + w * 512;           // wave-uniform base; HW scatters lane*16B
  __bf16* lA1 = As + 2048 + w * 512;
  __bf16* lB  = Bs + w * 512;
  const int quad = l >> 4;   // 0..3
  const int r16 = l & 15;    // 0..15
  f32x4 acc[2][4] = {};
  for (int k0 = 0; k0 < K; k0 += 32) {
    __builtin_amdgcn_global_load_lds((const __attribute__((address_space(1))) void*)(gA0 + k0),
                                     (__attribute__((address_space(3))) void*)lA0, 16, 0, 0);
    __builtin_amdgcn_global_load_lds((const __attribute__((address_space(1))) void*)(gA1 + k0),
                                     (__attribute__((address_space(3))) void*)lA1, 16, 0, 0);
    __builtin_amdgcn_global_load_lds((const __attribute__((address_space(1))) void*)(gB + k0),
                                     (__attribute__((address_space(3))) void*)lB, 16, 0, 0);
    __syncthreads();
    // A frag rows: w*32 + mt*16 + r16; k = quad*8 + j
    bf16x8 a0 = *(const bf16x8*)(As + (w * 32 + r16) * 32 + quad * 8);
    bf16x8 a1 = *(const bf16x8*)(As + (w * 32 + 16 + r16) * 32 + quad * 8);
    bf16x8 b0 = *(const bf16x8*)(Bs + (0 * 16 + r16) * 32 + quad * 8);
    bf16x8 b1 = *(const bf16x8*)(Bs + (1 * 16 + r16) * 32 + quad * 8);
    bf16x8 b2 = *(const bf16x8*)(Bs + (2 * 16 + r16) * 32 + quad * 8);
    bf16x8 b3 = *(const bf16x8*)(Bs + (3 * 16 + r16) * 32 + quad * 8);
    acc[0][0] = __builtin_amdgcn_mfma_f32_16x16x32_bf16(a0, b0, acc[0][0], 0, 0, 0);
    acc[0][1] = __builtin_amdgcn_mfma_f32_16x16x32_bf16(a0, b1, acc[0][1], 0, 0, 0);
    acc[0][2] = __builtin_amdgcn_mfma_f32_16x16x32_bf16(a0, b2, acc[0][2], 0, 0, 0);
    acc[0][3] = __builtin_amdgcn_mfma_f32_16x16x32_bf16(a0, b3, acc[0][3], 0, 0, 0);
    acc[1][0] = __builtin_amdgcn_mfma_f32_16x16x32_bf16(a1, b0, acc[1][0], 0, 0, 0);
    acc[1][1] = __builtin_amdgcn_mfma_f32_16x16x32_bf16(a1, b1, acc[1][1], 0, 0, 0);
    acc[1][2] = __builtin_amdgcn_mfma_f32_16x16x32_bf16(a1, b2, acc[1][2], 0, 0, 0);
    acc[1][3] = __builtin_amdgcn_mfma_f32_16x16x32_bf16(a1, b3, acc[1][3], 0, 0, 0);
    __syncthreads();
  }
  // C/D layout: col(n)=lane&15, row(m)=quad*4+reg
#pragma unroll
  for (int mt = 0; mt < 2; ++mt) {
    const int mrow = m0 + w * 32 + mt * 16 + quad * 4;
    const int ncol = n0 + r16;
#pragma unroll
    for (int r = 0; r < 4; ++r) {
      size_t rowoff = (size_t)(mrow + r) * N;
      C[rowoff + ncol]      = acc[mt][0][r];
      C[rowoff + ncol + 16] = acc[mt][1][r];
      C[rowoff + ncol + 32] = acc[mt][2][r];
      C[rowoff + ncol + 48] = acc[mt][3][r];
    }
  }
}

// ---------------- QK L2-norm + RoPE -> bf16, relayout to [head][t][d] ----------------
// QKVf row layout: [0,1024)=q heads, [1024,1280)=k heads, [1280,1536)=v heads.
// Qb gets the 1/sqrt(d)=0.125 softmax scale folded in (2^-3, exact in bf16).
__global__ __launch_bounds__(256) void norm_rope_kernel(const float* __restrict__ QKVf,
                                                        __bf16* __restrict__ Qb,
                                                        __bf16* __restrict__ Kb) {
  const int t = blockIdx.x;
  const int head = blockIdx.y * 4 + (threadIdx.x >> 6);
  const int j = threadIdx.x & 63;
  float v;
  if (head < NH) v = QKVf[(size_t)t * 1536 + head * HD + j];
  else           v = QKVf[(size_t)t * 1536 + 1024 + (head - NH) * HD + j];
  float ss = v * v;
#pragma unroll
  for (int off = 32; off; off >>= 1) ss += __shfl_xor(ss, off, 64);
  v *= 1.0f / (sqrtf(ss) + 1e-6f);
  float p = __shfl_xor(v, 32, 64);
  float rot = (j < 32) ? -p : p;
  const int i = j & 31;
  const float theta = exp2f(-(float)i * (13.287712379549449f / 32.0f));
  float ang = (float)t * theta;
  float s, c;
  sincosf(ang, &s, &c);
  float o = v * c + rot * s;
  if (head < NH) Qb[((size_t)head * T_SEQ + t) * HD + j] = (__bf16)(o * 0.125f);
  else           Kb[((size_t)(head - NH) * T_SEQ + t) * HD + j] = (__bf16)o;
}

// ---------------- V transpose: QKVf[t][1280 + kvh*64 + d] f32 -> Vt[kvh][d][t] bf16 ----------------
// grid (T/64, NKV), block 256
__global__ __launch_bounds__(256) void vtrans_kernel(const float* __restrict__ QKVf,
                                                     __bf16* __restrict__ Vt) {
  __shared__ float ls[64][65];
  const int kvh = blockIdx.y;
  const int tb = blockIdx.x * 64;
  const int tid = threadIdx.x;
  {
    int r = tid >> 2, c0 = (tid & 3) * 16;
#pragma unroll
    for (int i = 0; i < 16; i += 4) {
      float4 v = *(const float4*)(QKVf + (size_t)(tb + r) * 1536 + 1280 + kvh * 64 + c0 + i);
      ls[r][c0 + i] = v.x; ls[r][c0 + i + 1] = v.y;
      ls[r][c0 + i + 2] = v.z; ls[r][c0 + i + 3] = v.w;
    }
  }
  __syncthreads();
  {
    int d = tid >> 2, t0c = (tid & 3) * 16;
    bf16x8 o0, o1;
#pragma unroll
    for (int i = 0; i < 8; ++i) o0[i] = (__bf16)ls[t0c + i][d];
#pragma unroll
    for (int i = 0; i < 8; ++i) o1[i] = (__bf16)ls[t0c + 8 + i][d];
    __bf16* dst = Vt + ((size_t)kvh * HD + d) * T_SEQ + tb + t0c;
    *(bf16x8*)dst = o0;
    *(bf16x8*)(dst + 8) = o1;
  }
}

// ---------------- MFMA sliding-window attention ----------------
// grid (T/64, NH), block 256 (4 waves). Wave w owns queries [t0+w*16, t0+w*16+16).
// S = Q K^T (scale pre-folded into Qb; |s|<=0.125 so exp can't overflow -> no online max),
// P -> per-wave LDS (A-frag relayout, in-wave DS ordering so no barrier), O += P V on
// pre-transposed Vt. Row-sums in registers, shfl-reduced in epilogue.
__global__ __launch_bounds__(256) void attn_mfma_kernel(const __bf16* __restrict__ Qb,
                                                        const __bf16* __restrict__ Kb,
                                                        const __bf16* __restrict__ Vt,
                                                        __bf16* __restrict__ Yb) {
  __shared__ __align__(16) __bf16 Pl[4][16][72];
  const int h = blockIdx.y, kvh = h >> 2;
  const int t0 = blockIdx.x * 64;
  const int tid = threadIdx.x;
  const int w = tid >> 6, l = tid & 63;
  const int quad = l >> 4, r16 = l & 15;
  const __bf16* qptr = Qb + ((size_t)h * T_SEQ + t0 + w * 16 + r16) * HD + quad * 8;
  bf16x8 aq0 = *(const bf16x8*)(qptr);
  bf16x8 aq1 = *(const bf16x8*)(qptr + 32);
  const int j0 = max(0, t0 - WIN);
  const int nch = (t0 + 64 - j0) >> 6;
  const __bf16* kbase = Kb + (size_t)kvh * T_SEQ * HD;
  const __bf16* vbase = Vt + (size_t)kvh * HD * T_SEQ;
  const int tq_base = t0 + w * 16 + quad * 4;
  f32x4 oacc[4] = {};
  float lsum[4] = {0.f, 0.f, 0.f, 0.f};
  for (int c = 0; c < nch; ++c) {
    const int key0 = j0 + (c << 6);
    f32x4 s[4] = {};
#pragma unroll
    for (int nt = 0; nt < 4; ++nt) {
      const __bf16* kr = kbase + (size_t)(key0 + nt * 16 + r16) * HD + quad * 8;
      bf16x8 bk0 = *(const bf16x8*)kr;
      bf16x8 bk1 = *(const bf16x8*)(kr + 32);
      s[nt] = __builtin_amdgcn_mfma_f32_16x16x32_bf16(aq0, bk0, s[nt], 0, 0, 0);
      s[nt] = __builtin_amdgcn_mfma_f32_16x16x32_bf16(aq1, bk1, s[nt], 0, 0, 0);
    }
#pragma unroll
    for (int nt = 0; nt < 4; ++nt) {
      const int key = key0 + nt * 16 + r16;
#pragma unroll
      for (int r = 0; r < 4; ++r) {
        const int tq = tq_base + r;
        bool valid = (key <= tq) && (key > tq - WIN);
        float p = valid ? __expf(s[nt][r]) : 0.0f;
        lsum[r] += p;
        Pl[w][quad * 4 + r][nt * 16 + r16] = (__bf16)p;
      }
    }
    bf16x8 ap0 = *(const bf16x8*)(&Pl[w][r16][quad * 8]);
    bf16x8 ap1 = *(const bf16x8*)(&Pl[w][r16][32 + quad * 8]);
#pragma unroll
    for (int nt = 0; nt < 4; ++nt) {
      const __bf16* vr = vbase + (size_t)(nt * 16 + r16) * T_SEQ + key0 + quad * 8;
      bf16x8 bv0 = *(const bf16x8*)vr;
      bf16x8 bv1 = *(const bf16x8*)(vr + 32);
      oacc[nt] = __builtin_amdgcn_mfma_f32_16x16x32_bf16(ap0, bv0, oacc[nt], 0, 0, 0);
      oacc[nt] = __builtin_amdgcn_mfma_f32_16x16x32_bf16(ap1, bv1, oacc[nt], 0, 0, 0);
    }
  }
#pragma unroll
  for (int r = 0; r < 4; ++r) {
#pragma unroll
    for (int m = 1; m < 16; m <<= 1) lsum[r] += __shfl_xor(lsum[r], m, 64);
    lsum[r] = 1.0f / lsum[r];
  }
#pragma unroll
  for (int r = 0; r < 4; ++r) {
    size_t row = (size_t)(tq_base + r);
#pragma unroll
    for (int nt = 0; nt < 4; ++nt) {
      Yb[row * C_DIM + h * HD + nt * 16 + r16] = (__bf16)(oacc[nt][r] * lsum[r]);
    }
  }
}

extern "C" void kernel_launch(void* const* d_in, const int* in_sizes, int n_in,
                              void* d_out, int out_size, void* d_ws, size_t ws_size,
                              hipStream_t stream) {
  const float* x     = (const float*)d_in[0];
  const float* Wq    = (const float*)d_in[1];
  const float* Wkv   = (const float*)d_in[2];
  const float* Wproj = (const float*)d_in[3];
  float* out = (float*)d_out;

  // workspace layout
  __bf16* xb    = (__bf16*)d_ws;                      // [2048][1024]
  __bf16* Wqkvb = xb + (size_t)T_SEQ * C_DIM;         // [1536][1024] (Wq rows 0..1023, Wkv 1024..1535)
  __bf16* Wpb   = Wqkvb + (size_t)1536 * C_DIM;       // [1024][1024]
  float*  QKVf  = (float*)(Wpb + (size_t)C_DIM * C_DIM);  // [2048][1536] f32
  __bf16* Qb    = (__bf16*)(QKVf + (size_t)T_SEQ * 1536); // [16][2048][64]
  __bf16* Kb    = Qb + (size_t)NH * T_SEQ * HD;           // [4][2048][64]
  __bf16* Vt    = Kb + (size_t)NKV * T_SEQ * HD;          // [4][64][2048]
  __bf16* Yb    = Vt + (size_t)NKV * HD * T_SEQ;          // [2048][1024]

  // fused casts
  cast_all_kernel<<<4608, 256, 0, stream>>>(x, Wq, Wkv, Wproj, xb, Wqkvb, Wpb);

  // QKV = x @ [Wq;Wkv]^T  [2048,1536]
  gemm_nt128_kernel<<<dim3(1536 / 64, T_SEQ / 128), 256, 0, stream>>>(xb, Wqkvb, QKVf, T_SEQ, 1536, C_DIM);

  // L2 norm + RoPE -> bf16 layouts; V transpose -> Vt bf16
  norm_rope_kernel<<<dim3(T_SEQ, 5), 256, 0, stream>>>(QKVf, Qb, Kb);
  vtrans_kernel<<<dim3(T_SEQ / 64, NKV), 256, 0, stream>>>(QKVf, Vt);

  // MFMA sliding-window attention -> Yb (bf16)
  attn_mfma_kernel<<<dim3(T_SEQ / 64, NH), 256, 0, stream>>>(Qb, Kb, Vt, Yb);

  // out = Y @ Wproj^T
  gemm_nt128_kernel<<<dim3(C_DIM / 64, T_SEQ / 128), 256, 0, stream>>>(Yb, Wpb, out, T_SEQ, C_DIM, C_DIM);
}

// Round 5
// 145.800 us; speedup vs baseline: 11.6422x; 1.0997x over previous
//
#include <hip/hip_runtime.h>

#define T_SEQ 2048
#define C_DIM 1024
#define NH    16
#define NKV   4
#define HD    64
#define WIN   512

typedef __bf16 bf16x8 __attribute__((ext_vector_type(8)));
typedef __bf16 bf16x4 __attribute__((ext_vector_type(4)));
typedef float f32x4 __attribute__((ext_vector_type(4)));

#define MFMA16(a, b, c) __builtin_amdgcn_mfma_f32_16x16x32_bf16(a, b, c, 0, 0, 0)

// ---------------- prep: fused f32->bf16 casts + RoPE table ----------------
// blocks [0,2048): x  [2048,3072): Wq  [3072,3584): Wkv  [3584,4608): Wp
// blocks [4608,4864): ropeT[t][i] = {cos(t*theta_i), sin(t*theta_i)}, i in [0,32)
__global__ __launch_bounds__(256) void prep_kernel(const float* __restrict__ x,
                                                   const float* __restrict__ Wq,
                                                   const float* __restrict__ Wkv,
                                                   const float* __restrict__ Wp,
                                                   __bf16* __restrict__ xb,
                                                   __bf16* __restrict__ Wqkvb,
                                                   __bf16* __restrict__ Wpb,
                                                   float2* __restrict__ ropeT) {
  int b = blockIdx.x;
  if (b >= 4608) {
    int idx = (b - 4608) * 256 + threadIdx.x;  // < 65536
    int t = idx >> 5, i = idx & 31;
    float theta = exp2f(-(float)i * (13.287712379549449f / 32.0f));
    float s, c;
    sincosf((float)t * theta, &s, &c);
    ropeT[idx] = make_float2(c, s);
    return;
  }
  const float* src;
  __bf16* dst;
  int off;
  if (b < 2048)      { src = x;   dst = xb;                off = b; }
  else if (b < 3072) { src = Wq;  dst = Wqkvb;             off = b - 2048; }
  else if (b < 3584) { src = Wkv; dst = Wqkvb + (1 << 20); off = b - 3072; }
  else               { src = Wp;  dst = Wpb;               off = b - 3584; }
  int i = off * 1024 + threadIdx.x * 4;
  float4 v = *(const float4*)(src + i);
  bf16x4 o;
  o[0] = (__bf16)v.x; o[1] = (__bf16)v.y; o[2] = (__bf16)v.z; o[3] = (__bf16)v.w;
  *(bf16x4*)(dst + i) = o;
}

// ---------------- GEMM core: C128x64 tile, BK=64, VGPR-staged double-buffered LDS ----
// Grid is TLP-starved (1-1.5 blocks/CU) so latency hiding must come from ILP:
// global loads for iter i+1 issue before iter i's MFMAs; the vmcnt wait lands at the
// ds_write AFTER compute, so the load flies over 16 MFMAs. One barrier per iter.
// LDS rows are 64 bf16 (128 B); 16B chunks XOR-swizzled by (row&7) to spread banks
// (unswizzled BK=64 puts all 16 r16-lanes of a quad on the same 4 banks).
__device__ __forceinline__ void gemm_core(const __bf16* __restrict__ A,
                                          const __bf16* __restrict__ B,
                                          int K, int m0, int n0,
                                          __bf16* AsB, __bf16* BsB,
                                          f32x4 (&acc)[2][4]) {
  const int tid = threadIdx.x;
  const int w = tid >> 6, l = tid & 63;
  const int quad = l >> 4, r16 = l & 15;
  const int arow = tid >> 1;
  const int brow = tid >> 2;
  const __bf16* gA = A + (size_t)(m0 + arow) * K + (tid & 1) * 32;
  const __bf16* gB = B + (size_t)(n0 + brow) * K + (tid & 3) * 16;
  int wA[4], wB[2];
#pragma unroll
  for (int q = 0; q < 4; ++q) wA[q] = arow * 64 + ((((tid & 1) * 4 + q) ^ (arow & 7)) * 8);
#pragma unroll
  for (int q = 0; q < 2; ++q) wB[q] = brow * 64 + ((((tid & 3) * 2 + q) ^ (brow & 7)) * 8);
  int rA[2][2], rB[4][2];
#pragma unroll
  for (int mt = 0; mt < 2; ++mt)
#pragma unroll
    for (int ks = 0; ks < 2; ++ks) {
      int row = w * 32 + mt * 16 + r16;
      rA[mt][ks] = row * 64 + (((ks * 4 + quad) ^ (row & 7)) * 8);
    }
#pragma unroll
  for (int nt = 0; nt < 4; ++nt)
#pragma unroll
    for (int ks = 0; ks < 2; ++ks) {
      int row = nt * 16 + r16;
      rB[nt][ks] = row * 64 + (((ks * 4 + quad) ^ (row & 7)) * 8);
    }
  const int nIter = K >> 6;
  uint4 pa[4], pb[2];
  {
    const uint4* a = (const uint4*)gA;
    pa[0] = a[0]; pa[1] = a[1]; pa[2] = a[2]; pa[3] = a[3];
    const uint4* b = (const uint4*)gB;
    pb[0] = b[0]; pb[1] = b[1];
  }
#pragma unroll
  for (int q = 0; q < 4; ++q) *(uint4*)(AsB + wA[q]) = pa[q];
#pragma unroll
  for (int q = 0; q < 2; ++q) *(uint4*)(BsB + wB[q]) = pb[q];
  __syncthreads();
  int cur = 0;
  for (int it = 0; it < nIter; ++it) {
    if (it + 1 < nIter) {  // prefetch next K-slab into VGPRs (no wait here)
      const uint4* a = (const uint4*)(gA + ((it + 1) << 6));
      pa[0] = a[0]; pa[1] = a[1]; pa[2] = a[2]; pa[3] = a[3];
      const uint4* b = (const uint4*)(gB + ((it + 1) << 6));
      pb[0] = b[0]; pb[1] = b[1];
    }
    const __bf16* Asc = AsB + cur * 8192;
    const __bf16* Bsc = BsB + cur * 4096;
#pragma unroll
    for (int ks = 0; ks < 2; ++ks) {
      bf16x8 a0 = *(const bf16x8*)(Asc + rA[0][ks]);
      bf16x8 a1 = *(const bf16x8*)(Asc + rA[1][ks]);
      bf16x8 b0 = *(const bf16x8*)(Bsc + rB[0][ks]);
      bf16x8 b1 = *(const bf16x8*)(Bsc + rB[1][ks]);
      bf16x8 b2 = *(const bf16x8*)(Bsc + rB[2][ks]);
      bf16x8 b3 = *(const bf16x8*)(Bsc + rB[3][ks]);
      acc[0][0] = MFMA16(a0, b0, acc[0][0]);
      acc[0][1] = MFMA16(a0, b1, acc[0][1]);
      acc[0][2] = MFMA16(a0, b2, acc[0][2]);
      acc[0][3] = MFMA16(a0, b3, acc[0][3]);
      acc[1][0] = MFMA16(a1, b0, acc[1][0]);
      acc[1][1] = MFMA16(a1, b1, acc[1][1]);
      acc[1][2] = MFMA16(a1, b2, acc[1][2]);
      acc[1][3] = MFMA16(a1, b3, acc[1][3]);
    }
    if (it + 1 < nIter) {
      __builtin_amdgcn_sched_barrier(0);  // keep prefetch+MFMA above the vmcnt-waiting writes
      __bf16* Asn = AsB + (cur ^ 1) * 8192;
      __bf16* Bsn = BsB + (cur ^ 1) * 4096;
#pragma unroll
      for (int q = 0; q < 4; ++q) *(uint4*)(Asn + wA[q]) = pa[q];
#pragma unroll
      for (int q = 0; q < 2; ++q) *(uint4*)(Bsn + wB[q]) = pb[q];
      __syncthreads();
      cur ^= 1;
    }
  }
}

// ---------------- QKV GEMM with fused norm+RoPE (Q,K) and V-transpose epilogue ----------
// N-tiles: [0,16): Q head n0/64; [16,20): K head; [20,24): V head.
// acc[mt][nt][r] = C(row m0+w*32+mt*16+quad*4+r, col n0+nt*16+r16).
// L2 norm over the 64 cols = sum over nt + shfl_xor over r16 lanes. RoPE pairs
// j <-> j+-32 = nt <-> nt+-2, i.e. purely in-register.
__global__ __launch_bounds__(256) void gemm_qkv_kernel(const __bf16* __restrict__ xb,
                                                       const __bf16* __restrict__ Wqkvb,
                                                       const float2* __restrict__ ropeT,
                                                       __bf16* __restrict__ Qb,
                                                       __bf16* __restrict__ Kb,
                                                       __bf16* __restrict__ Vt) {
  __shared__ __align__(16) __bf16 As[2 * 8192];
  __shared__ __align__(16) __bf16 Bs[2 * 4096];
  f32x4 acc[2][4] = {};
  const int m0 = blockIdx.y * 128, n0 = blockIdx.x * 64;
  gemm_core(xb, Wqkvb, C_DIM, m0, n0, As, Bs, acc);
  const int tid = threadIdx.x;
  const int w = tid >> 6, l = tid & 63, quad = l >> 4, r16 = l & 15;
  if (n0 < 1280) {  // Q or K: L2-norm + RoPE
    const bool isQ = n0 < 1024;
    const int head = isQ ? (n0 >> 6) : ((n0 - 1024) >> 6);
    __bf16* dstBase = (isQ ? Qb : Kb) + (size_t)head * T_SEQ * HD;
    const float osc = isQ ? 0.125f : 1.0f;  // fold softmax scale into Q (2^-3 exact)
#pragma unroll
    for (int mt = 0; mt < 2; ++mt) {
#pragma unroll
      for (int r = 0; r < 4; ++r) {
        float ss = acc[mt][0][r] * acc[mt][0][r] + acc[mt][1][r] * acc[mt][1][r] +
                   acc[mt][2][r] * acc[mt][2][r] + acc[mt][3][r] * acc[mt][3][r];
#pragma unroll
        for (int m = 1; m < 16; m <<= 1) ss += __shfl_xor(ss, m, 64);
        const float inv = osc / (sqrtf(ss) + 1e-6f);
        const int t = m0 + w * 32 + mt * 16 + quad * 4 + r;
        const float2 cs0 = ropeT[t * 32 + r16];       // i = r16      (j = r16, 32+r16)
        const float2 cs1 = ropeT[t * 32 + 16 + r16];  // i = 16+r16   (j = 16+r16, 48+r16)
        const float v0 = acc[mt][0][r] * inv, v1 = acc[mt][1][r] * inv;
        const float v2 = acc[mt][2][r] * inv, v3 = acc[mt][3][r] * inv;
        __bf16* dst = dstBase + (size_t)t * HD;
        dst[r16]      = (__bf16)(v0 * cs0.x - v2 * cs0.y);
        dst[16 + r16] = (__bf16)(v1 * cs1.x - v3 * cs1.y);
        dst[32 + r16] = (__bf16)(v2 * cs0.x + v0 * cs0.y);
        dst[48 + r16] = (__bf16)(v3 * cs1.x + v1 * cs1.y);
      }
    }
  } else {  // V: transpose to Vt[kvh][d][t] via reused LDS
    const int kvh = (n0 - 1280) >> 6;
    __syncthreads();  // all waves done reading As
    __bf16* Vs = As;  // [64 d][stride 136]
#pragma unroll
    for (int mt = 0; mt < 2; ++mt)
#pragma unroll
      for (int nt = 0; nt < 4; ++nt)
#pragma unroll
        for (int r = 0; r < 4; ++r)
          Vs[(nt * 16 + r16) * 136 + w * 32 + mt * 16 + quad * 4 + r] = (__bf16)acc[mt][nt][r];
    __syncthreads();
    const int d = tid >> 2, tc = (tid & 3) * 32;
    __bf16* dst = Vt + ((size_t)kvh * HD + d) * T_SEQ + m0 + tc;
#pragma unroll
    for (int c2 = 0; c2 < 4; ++c2) {
      bf16x8 v = *(const bf16x8*)(Vs + d * 136 + tc + c2 * 8);
      *(bf16x8*)(dst + c2 * 8) = v;
    }
  }
}

// ---------------- proj GEMM: plain f32 epilogue ----------------
__global__ __launch_bounds__(256) void gemm_proj_kernel(const __bf16* __restrict__ Yb,
                                                        const __bf16* __restrict__ Wpb,
                                                        float* __restrict__ C) {
  __shared__ __align__(16) __bf16 As[2 * 8192];
  __shared__ __align__(16) __bf16 Bs[2 * 4096];
  f32x4 acc[2][4] = {};
  const int m0 = blockIdx.y * 128, n0 = blockIdx.x * 64;
  gemm_core(Yb, Wpb, C_DIM, m0, n0, As, Bs, acc);
  const int tid = threadIdx.x;
  const int w = tid >> 6, l = tid & 63, quad = l >> 4, r16 = l & 15;
#pragma unroll
  for (int mt = 0; mt < 2; ++mt) {
    const int mrow = m0 + w * 32 + mt * 16 + quad * 4;
    const int ncol = n0 + r16;
#pragma unroll
    for (int r = 0; r < 4; ++r) {
      size_t rowoff = (size_t)(mrow + r) * C_DIM;
      C[rowoff + ncol]      = acc[mt][0][r];
      C[rowoff + ncol + 16] = acc[mt][1][r];
      C[rowoff + ncol + 32] = acc[mt][2][r];
      C[rowoff + ncol + 48] = acc[mt][3][r];
    }
  }
}

// ---------------- MFMA sliding-window attention (unchanged from R3) ----------------
__global__ __launch_bounds__(256) void attn_mfma_kernel(const __bf16* __restrict__ Qb,
                                                        const __bf16* __restrict__ Kb,
                                                        const __bf16* __restrict__ Vt,
                                                        __bf16* __restrict__ Yb) {
  __shared__ __align__(16) __bf16 Pl[4][16][72];
  const int h = blockIdx.y, kvh = h >> 2;
  const int t0 = blockIdx.x * 64;
  const int tid = threadIdx.x;
  const int w = tid >> 6, l = tid & 63;
  const int quad = l >> 4, r16 = l & 15;
  const __bf16* qptr = Qb + ((size_t)h * T_SEQ + t0 + w * 16 + r16) * HD + quad * 8;
  bf16x8 aq0 = *(const bf16x8*)(qptr);
  bf16x8 aq1 = *(const bf16x8*)(qptr + 32);
  const int j0 = max(0, t0 - WIN);
  const int nch = (t0 + 64 - j0) >> 6;
  const __bf16* kbase = Kb + (size_t)kvh * T_SEQ * HD;
  const __bf16* vbase = Vt + (size_t)kvh * HD * T_SEQ;
  const int tq_base = t0 + w * 16 + quad * 4;
  f32x4 oacc[4] = {};
  float lsum[4] = {0.f, 0.f, 0.f, 0.f};
  for (int c = 0; c < nch; ++c) {
    const int key0 = j0 + (c << 6);
    f32x4 s[4] = {};
#pragma unroll
    for (int nt = 0; nt < 4; ++nt) {
      const __bf16* kr = kbase + (size_t)(key0 + nt * 16 + r16) * HD + quad * 8;
      bf16x8 bk0 = *(const bf16x8*)kr;
      bf16x8 bk1 = *(const bf16x8*)(kr + 32);
      s[nt] = MFMA16(aq0, bk0, s[nt]);
      s[nt] = MFMA16(aq1, bk1, s[nt]);
    }
#pragma unroll
    for (int nt = 0; nt < 4; ++nt) {
      const int key = key0 + nt * 16 + r16;
#pragma unroll
      for (int r = 0; r < 4; ++r) {
        const int tq = tq_base + r;
        bool valid = (key <= tq) && (key > tq - WIN);
        float p = valid ? __expf(s[nt][r]) : 0.0f;
        lsum[r] += p;
        Pl[w][quad * 4 + r][nt * 16 + r16] = (__bf16)p;
      }
    }
    bf16x8 ap0 = *(const bf16x8*)(&Pl[w][r16][quad * 8]);
    bf16x8 ap1 = *(const bf16x8*)(&Pl[w][r16][32 + quad * 8]);
#pragma unroll
    for (int nt = 0; nt < 4; ++nt) {
      const __bf16* vr = vbase + (size_t)(nt * 16 + r16) * T_SEQ + key0 + quad * 8;
      bf16x8 bv0 = *(const bf16x8*)vr;
      bf16x8 bv1 = *(const bf16x8*)(vr + 32);
      oacc[nt] = MFMA16(ap0, bv0, oacc[nt]);
      oacc[nt] = MFMA16(ap1, bv1, oacc[nt]);
    }
  }
#pragma unroll
  for (int r = 0; r < 4; ++r) {
#pragma unroll
    for (int m = 1; m < 16; m <<= 1) lsum[r] += __shfl_xor(lsum[r], m, 64);
    lsum[r] = 1.0f / lsum[r];
  }
#pragma unroll
  for (int r = 0; r < 4; ++r) {
    size_t row = (size_t)(tq_base + r);
#pragma unroll
    for (int nt = 0; nt < 4; ++nt) {
      Yb[row * C_DIM + h * HD + nt * 16 + r16] = (__bf16)(oacc[nt][r] * lsum[r]);
    }
  }
}

extern "C" void kernel_launch(void* const* d_in, const int* in_sizes, int n_in,
                              void* d_out, int out_size, void* d_ws, size_t ws_size,
                              hipStream_t stream) {
  const float* x     = (const float*)d_in[0];
  const float* Wq    = (const float*)d_in[1];
  const float* Wkv   = (const float*)d_in[2];
  const float* Wproj = (const float*)d_in[3];
  float* out = (float*)d_out;

  // workspace layout (bf16 elements)
  __bf16* xb    = (__bf16*)d_ws;                        // [2048][1024]
  __bf16* Wqkvb = xb + (size_t)T_SEQ * C_DIM;           // [1536][1024]
  __bf16* Wpb   = Wqkvb + (size_t)1536 * C_DIM;         // [1024][1024]
  __bf16* Qb    = Wpb + (size_t)C_DIM * C_DIM;          // [16][2048][64]
  __bf16* Kb    = Qb + (size_t)NH * T_SEQ * HD;         // [4][2048][64]
  __bf16* Vt    = Kb + (size_t)NKV * T_SEQ * HD;        // [4][64][2048]
  __bf16* Yb    = Vt + (size_t)NKV * HD * T_SEQ;        // [2048][1024]
  float2* ropeT = (float2*)(Yb + (size_t)T_SEQ * C_DIM); // [2048][32] {cos,sin}

  prep_kernel<<<4864, 256, 0, stream>>>(x, Wq, Wkv, Wproj, xb, Wqkvb, Wpb, ropeT);
  gemm_qkv_kernel<<<dim3(24, 16), 256, 0, stream>>>(xb, Wqkvb, ropeT, Qb, Kb, Vt);
  attn_mfma_kernel<<<dim3(T_SEQ / 64, NH), 256, 0, stream>>>(Qb, Kb, Vt, Yb);
  gemm_proj_kernel<<<dim3(16, 16), 256, 0, stream>>>(Yb, Wpb, out);
}